// Round 2
// baseline (309.463 us; speedup 1.0000x reference)
//
#include <hip/hip_runtime.h>
#include <math.h>

#define TOTAL 2560
#define DIM 512
#define HEADS 8
#define HD 64
#define NEG_BIG (-1e30f)

// ---------------- positional encoding ----------------
__global__ __launch_bounds__(64) void pos_kernel(
    const float* __restrict__ coords,
    const float* __restrict__ pos_w,
    const float* __restrict__ pos_b,
    float* __restrict__ pos_out)
{
    __shared__ float enc[100];
    const int p = blockIdx.x;
    const int t = threadIdx.x;
    const float c0 = coords[p * 3 + 0];
    const float c1 = coords[p * 3 + 1];
    const float c2 = coords[p * 3 + 2];
    for (int i = t; i < 99; i += 64) {
        float v;
        if (i < 96) {
            const int d = i >> 5;          // which coordinate
            const int j = i & 31;          // 0..15 sin, 16..31 cos
            const float cv = (d == 0) ? c0 : ((d == 1) ? c1 : c2);
            const float freq = exp2f((float)(j & 15)) * 3.14159265358979323846f;
            const float sc = cv * freq;    // fp32 product, matches reference rounding
            v = (j < 16) ? (float)sin((double)sc) : (float)cos((double)sc);
        } else {
            v = (i == 96) ? c0 : ((i == 97) ? c1 : c2);
        }
        enc[i] = v;
    }
    __syncthreads();
    float acc = pos_b[t];
    const float* w = pos_w + t * 99;
    for (int i = 0; i < 99; ++i) acc = fmaf(enc[i], w[i], acc);
    pos_out[p * 64 + t] = acc;
}

// ---------------- QKV GEMM (fp32, 64x64 tile, 4x4 micro) ----------------
__global__ __launch_bounds__(256) void qkv_gemm_kernel(
    const float* __restrict__ A,
    const float* __restrict__ W,
    const float* __restrict__ pos,
    float* __restrict__ qkv)
{
    __shared__ float As[16][68];
    __shared__ float Bs[16][68];
    const int m0 = blockIdx.x * 64;
    const int n0 = blockIdx.y * 64;
    const int t  = threadIdx.x;
    const int tx = t & 15, ty = t >> 4;
    const int lr = t >> 2, lc = (t & 3) * 4;
    float acc[4][4] = {{0.f}};
    const float* aptr = A + (m0 + lr) * 512 + lc;
    const float* bptr = W + (n0 + lr) * 512 + lc;
    for (int kt = 0; kt < 512; kt += 16) {
        const float4 a4 = *(const float4*)(aptr + kt);
        const float4 b4 = *(const float4*)(bptr + kt);
        __syncthreads();
        As[lc + 0][lr] = a4.x; As[lc + 1][lr] = a4.y; As[lc + 2][lr] = a4.z; As[lc + 3][lr] = a4.w;
        Bs[lc + 0][lr] = b4.x; Bs[lc + 1][lr] = b4.y; Bs[lc + 2][lr] = b4.z; Bs[lc + 3][lr] = b4.w;
        __syncthreads();
#pragma unroll
        for (int kk = 0; kk < 16; ++kk) {
            const float4 av = *(const float4*)&As[kk][ty * 4];
            const float4 bv = *(const float4*)&Bs[kk][tx * 4];
            const float a[4] = {av.x, av.y, av.z, av.w};
            const float b[4] = {bv.x, bv.y, bv.z, bv.w};
#pragma unroll
            for (int i = 0; i < 4; ++i)
#pragma unroll
                for (int j = 0; j < 4; ++j)
                    acc[i][j] = fmaf(a[i], b[j], acc[i][j]);
        }
    }
#pragma unroll
    for (int i = 0; i < 4; ++i) {
        const int p = m0 + ty * 4 + i;
#pragma unroll
        for (int j = 0; j < 4; ++j) {
            const int col = n0 + tx * 4 + j;
            const int which = col >> 9;      // 0=q 1=k 2=v
            const int h  = (col >> 6) & 7;
            const int dd = col & 63;
            float v = acc[i][j];
            if (which < 2) v += pos[p * 64 + dd];
            qkv[((which * 8 + h) * TOTAL + p) * 64 + dd] = v;
        }
    }
}

// ---------------- flash attention (fp32) ----------------
// grid: x=q-tile, y=head, z=batch. batch0: 512 real q/k + 1536 analytic zero-keys.
// batch1: 2048x2048, mask(q<512 & k<512) handled by k-tile skip.
__global__ __launch_bounds__(256) void attn_kernel(
    const float* __restrict__ qkv,
    float* __restrict__ y)
{
    const int qt = blockIdx.x;
    const int h  = blockIdx.y;
    const int b  = blockIdx.z;
    const int nq = b ? 2048 : 512;
    if (qt * 64 >= nq) return;
    const int base = b ? 512 : 0;
    const int nkt  = nq >> 6;
    const int kt0  = (b && (qt * 64 < 512)) ? 8 : 0;
    const float extra = b ? 0.0f : 1536.0f;

    const float* Q = qkv + (0 * 8 + h) * (TOTAL * 64) + base * 64;
    const float* K = qkv + (1 * 8 + h) * (TOTAL * 64) + base * 64;
    const float* V = qkv + (2 * 8 + h) * (TOTAL * 64) + base * 64;

    __shared__ float Qs[64][68];   // [d][q]
    __shared__ float Ks[64][68];   // [d][k]
    __shared__ float Vs[64][68];   // [k][d]
    __shared__ float Ps[64][69];   // [k][q]
    __shared__ float mrow[64], lrow[64], crow[64];

    const int t  = threadIdx.x;
    const int tx = t & 15, ty = t >> 4;

    // stage Q tile: 64x64 floats = 1024 float4s = 256 threads x 4
#pragma unroll
    for (int i = 0; i < 4; ++i) {
        const int e4 = t + i * 256;
        const int r = e4 >> 4;
        const int c = (e4 & 15) * 4;
        const float4 q4 = *(const float4*)(Q + (qt * 64 + r) * 64 + c);
        Qs[c + 0][r] = q4.x; Qs[c + 1][r] = q4.y; Qs[c + 2][r] = q4.z; Qs[c + 3][r] = q4.w;
    }
    if (t < 64) { mrow[t] = NEG_BIG; lrow[t] = 0.0f; }
    float o[4][4] = {{0.f}};

    for (int kt = kt0; kt < nkt; ++kt) {
        float4 kreg[4], vreg[4];
#pragma unroll
        for (int i = 0; i < 4; ++i) {
            const int e4 = t + i * 256;
            const int r = e4 >> 4;
            const int c = (e4 & 15) * 4;
            kreg[i] = *(const float4*)(K + (kt * 64 + r) * 64 + c);
            vreg[i] = *(const float4*)(V + (kt * 64 + r) * 64 + c);
        }
        __syncthreads();   // prior iteration's reads of Ks/Vs complete
#pragma unroll
        for (int i = 0; i < 4; ++i) {
            const int e4 = t + i * 256;
            const int r = e4 >> 4;
            const int c = (e4 & 15) * 4;
            Ks[c + 0][r] = kreg[i].x; Ks[c + 1][r] = kreg[i].y; Ks[c + 2][r] = kreg[i].z; Ks[c + 3][r] = kreg[i].w;
            Vs[r][c + 0] = vreg[i].x; Vs[r][c + 1] = vreg[i].y; Vs[r][c + 2] = vreg[i].z; Vs[r][c + 3] = vreg[i].w;
        }
        __syncthreads();

        // S = Q^T K (over d), 4x4 per thread
        float s[4][4] = {{0.f}};
#pragma unroll 8
        for (int d = 0; d < 64; ++d) {
            const float4 av = *(const float4*)&Qs[d][ty * 4];
            const float4 bv = *(const float4*)&Ks[d][tx * 4];
            const float a[4] = {av.x, av.y, av.z, av.w};
            const float bb[4] = {bv.x, bv.y, bv.z, bv.w};
#pragma unroll
            for (int i = 0; i < 4; ++i)
#pragma unroll
                for (int j = 0; j < 4; ++j)
                    s[i][j] = fmaf(a[i], bb[j], s[i][j]);
        }
#pragma unroll
        for (int i = 0; i < 4; ++i)
#pragma unroll
            for (int j = 0; j < 4; ++j)
                Ps[tx * 4 + j][ty * 4 + i] = s[i][j] * 0.125f;
        __syncthreads();

        // online softmax, one row per lane (threads 0..63)
        if (t < 64) {
            const int r = t;
            const float m_old = mrow[r];
            float tm = NEG_BIG;
            for (int c = 0; c < 64; ++c) tm = fmaxf(tm, Ps[c][r]);
            const float m_new = fmaxf(m_old, tm);
            const float corr = __expf(m_old - m_new);
            float sum = 0.f;
            for (int c = 0; c < 64; ++c) {
                const float pv = __expf(Ps[c][r] - m_new);
                Ps[c][r] = pv;
                sum += pv;
            }
            mrow[r] = m_new;
            lrow[r] = lrow[r] * corr + sum;
            crow[r] = corr;
        }
        __syncthreads();

        // O = O*corr + P V
        float cr[4];
#pragma unroll
        for (int i = 0; i < 4; ++i) cr[i] = crow[ty * 4 + i];
#pragma unroll
        for (int i = 0; i < 4; ++i)
#pragma unroll
            for (int j = 0; j < 4; ++j) o[i][j] *= cr[i];
#pragma unroll 8
        for (int k = 0; k < 64; ++k) {
            const float4 bv = *(const float4*)&Vs[k][tx * 4];
            const float bb[4] = {bv.x, bv.y, bv.z, bv.w};
            const float a0 = Ps[k][ty * 4 + 0];
            const float a1 = Ps[k][ty * 4 + 1];
            const float a2 = Ps[k][ty * 4 + 2];
            const float a3 = Ps[k][ty * 4 + 3];
#pragma unroll
            for (int j = 0; j < 4; ++j) {
                o[0][j] = fmaf(a0, bb[j], o[0][j]);
                o[1][j] = fmaf(a1, bb[j], o[1][j]);
                o[2][j] = fmaf(a2, bb[j], o[2][j]);
                o[3][j] = fmaf(a3, bb[j], o[3][j]);
            }
        }
    }

    // finalize: analytic zero-score keys (batch0) + normalize
#pragma unroll
    for (int i = 0; i < 4; ++i) {
        const int r = ty * 4 + i;
        float m = mrow[r], l = lrow[r];
        float so = 1.0f;
        if (extra > 0.0f) {
            const float mn = fmaxf(m, 0.0f);
            const float cc = __expf(m - mn);
            l = l * cc + extra * __expf(-mn);
            so = cc;
        }
        const float inv = so / l;
        const int row = base + qt * 64 + r;
#pragma unroll
        for (int j = 0; j < 4; ++j)
            y[row * 512 + h * 64 + tx * 4 + j] = o[i][j] * inv;
    }
}

// ---------------- output projection (fp32, +bias) ----------------
__global__ __launch_bounds__(256) void proj_gemm_kernel(
    const float* __restrict__ A,     // y_ws [TOTAL][512]
    const float* __restrict__ W,     // proj_w [512][512] (N x K)
    const float* __restrict__ bias,
    float* __restrict__ out)
{
    __shared__ float As[16][68];
    __shared__ float Bs[16][68];
    const int m0 = blockIdx.x * 64;
    const int n0 = blockIdx.y * 64;
    const int t  = threadIdx.x;
    const int tx = t & 15, ty = t >> 4;
    const int lr = t >> 2, lc = (t & 3) * 4;
    float acc[4][4] = {{0.f}};
    const float* aptr = A + (m0 + lr) * 512 + lc;
    const float* bptr = W + (n0 + lr) * 512 + lc;
    for (int kt = 0; kt < 512; kt += 16) {
        const float4 a4 = *(const float4*)(aptr + kt);
        const float4 b4 = *(const float4*)(bptr + kt);
        __syncthreads();
        As[lc + 0][lr] = a4.x; As[lc + 1][lr] = a4.y; As[lc + 2][lr] = a4.z; As[lc + 3][lr] = a4.w;
        Bs[lc + 0][lr] = b4.x; Bs[lc + 1][lr] = b4.y; Bs[lc + 2][lr] = b4.z; Bs[lc + 3][lr] = b4.w;
        __syncthreads();
#pragma unroll
        for (int kk = 0; kk < 16; ++kk) {
            const float4 av = *(const float4*)&As[kk][ty * 4];
            const float4 bv = *(const float4*)&Bs[kk][tx * 4];
            const float a[4] = {av.x, av.y, av.z, av.w};
            const float b[4] = {bv.x, bv.y, bv.z, bv.w};
#pragma unroll
            for (int i = 0; i < 4; ++i)
#pragma unroll
                for (int j = 0; j < 4; ++j)
                    acc[i][j] = fmaf(a[i], b[j], acc[i][j]);
        }
    }
#pragma unroll
    for (int i = 0; i < 4; ++i) {
        const int p = m0 + ty * 4 + i;
#pragma unroll
        for (int j = 0; j < 4; ++j) {
            const int col = n0 + tx * 4 + j;
            out[p * 512 + col] = acc[i][j] + bias[col];
        }
    }
}

extern "C" void kernel_launch(void* const* d_in, const int* in_sizes, int n_in,
                              void* d_out, int out_size, void* d_ws, size_t ws_size,
                              hipStream_t stream) {
    const float* features = (const float*)d_in[0];
    const float* coords   = (const float*)d_in[1];
    const float* qkv_w    = (const float*)d_in[2];
    const float* proj_w   = (const float*)d_in[3];
    const float* proj_b   = (const float*)d_in[4];
    const float* pos_w    = (const float*)d_in[5];
    const float* pos_b    = (const float*)d_in[6];
    float* out = (float*)d_out;

    float* ws      = (float*)d_ws;
    float* pos_ws  = ws;                           // 2560*64
    float* qkv_ws  = pos_ws + TOTAL * 64;          // 3*8*2560*64
    float* y_ws    = qkv_ws + 3 * 8 * TOTAL * 64;  // 2560*512

    pos_kernel<<<dim3(TOTAL), dim3(64), 0, stream>>>(coords, pos_w, pos_b, pos_ws);
    qkv_gemm_kernel<<<dim3(TOTAL / 64, 1536 / 64), dim3(256), 0, stream>>>(
        features, qkv_w, pos_ws, qkv_ws);
    attn_kernel<<<dim3(32, HEADS, 2), dim3(256), 0, stream>>>(qkv_ws, y_ws);
    proj_gemm_kernel<<<dim3(TOTAL / 64, 512 / 64), dim3(256), 0, stream>>>(
        y_ws, proj_w, proj_b, out);
}

// Round 3
// 156.167 us; speedup vs baseline: 1.9816x; 1.9816x over previous
//
#include <hip/hip_runtime.h>
#include <math.h>

#define TOTAL 2560
#define NEG_BIG (-1e30f)

typedef __bf16 bf16x8 __attribute__((ext_vector_type(8)));
typedef float f32x4 __attribute__((ext_vector_type(4)));
typedef unsigned short ushort8v __attribute__((ext_vector_type(8)));

__device__ inline unsigned short f2bf(float f) {
    unsigned u = __builtin_bit_cast(unsigned, f);
    u += 0x7fff + ((u >> 16) & 1);
    return (unsigned short)(u >> 16);
}

// ---------------- positional encoding ----------------
__global__ __launch_bounds__(64) void pos_kernel(
    const float* __restrict__ coords,
    const float* __restrict__ pos_w,
    const float* __restrict__ pos_b,
    float* __restrict__ pos_out)
{
    __shared__ float enc[100];
    const int p = blockIdx.x;
    const int t = threadIdx.x;
    const float c0 = coords[p * 3 + 0];
    const float c1 = coords[p * 3 + 1];
    const float c2 = coords[p * 3 + 2];
    for (int i = t; i < 99; i += 64) {
        float v;
        if (i < 96) {
            const int d = i >> 5;
            const int j = i & 31;
            const float cv = (d == 0) ? c0 : ((d == 1) ? c1 : c2);
            const float freq = exp2f((float)(j & 15)) * 3.14159265358979323846f;
            const float sc = cv * freq;
            v = (j < 16) ? (float)sin((double)sc) : (float)cos((double)sc);
        } else {
            v = (i == 96) ? c0 : ((i == 97) ? c1 : c2);
        }
        enc[i] = v;
    }
    __syncthreads();
    float acc = pos_b[t];
    const float* w = pos_w + t * 99;
    for (int i = 0; i < 99; ++i) acc = fmaf(enc[i], w[i], acc);
    pos_out[p * 64 + t] = acc;
}

// ---------------- QKV GEMM (fp32 compute, bf16 output) ----------------
__global__ __launch_bounds__(256) void qkv_gemm_kernel(
    const float* __restrict__ A,
    const float* __restrict__ W,
    const float* __restrict__ pos,
    unsigned short* __restrict__ q_ws,
    unsigned short* __restrict__ k_ws,
    unsigned short* __restrict__ v_ws)
{
    __shared__ float As[16][68];
    __shared__ float Bs[16][68];
    const int m0 = blockIdx.x * 64;
    const int n0 = blockIdx.y * 64;
    const int t  = threadIdx.x;
    const int tx = t & 15, ty = t >> 4;
    const int lr = t >> 2, lc = (t & 3) * 4;
    float acc[4][4] = {{0.f}};
    const float* aptr = A + (m0 + lr) * 512 + lc;
    const float* bptr = W + (n0 + lr) * 512 + lc;
    for (int kt = 0; kt < 512; kt += 16) {
        const float4 a4 = *(const float4*)(aptr + kt);
        const float4 b4 = *(const float4*)(bptr + kt);
        __syncthreads();
        As[lc + 0][lr] = a4.x; As[lc + 1][lr] = a4.y; As[lc + 2][lr] = a4.z; As[lc + 3][lr] = a4.w;
        Bs[lc + 0][lr] = b4.x; Bs[lc + 1][lr] = b4.y; Bs[lc + 2][lr] = b4.z; Bs[lc + 3][lr] = b4.w;
        __syncthreads();
#pragma unroll
        for (int kk = 0; kk < 16; ++kk) {
            const float4 av = *(const float4*)&As[kk][ty * 4];
            const float4 bv = *(const float4*)&Bs[kk][tx * 4];
            const float a[4] = {av.x, av.y, av.z, av.w};
            const float b[4] = {bv.x, bv.y, bv.z, bv.w};
#pragma unroll
            for (int i = 0; i < 4; ++i)
#pragma unroll
                for (int j = 0; j < 4; ++j)
                    acc[i][j] = fmaf(a[i], b[j], acc[i][j]);
        }
    }
#pragma unroll
    for (int i = 0; i < 4; ++i) {
        const int p = m0 + ty * 4 + i;
#pragma unroll
        for (int j = 0; j < 4; ++j) {
            const int col = n0 + tx * 4 + j;
            const int which = col >> 9;      // 0=q 1=k 2=v
            const int h  = (col >> 6) & 7;
            const int dd = col & 63;
            float v = acc[i][j];
            if (which < 2) v += pos[p * 64 + dd];
            const unsigned short bv = f2bf(v);
            const int idx = (h * TOTAL + p) * 64 + dd;
            if (which == 0)      q_ws[idx] = bv;
            else if (which == 1) k_ws[idx] = bv;
            else                 v_ws[idx] = bv;
        }
    }
}

// ---------------- V transpose: [h][p][d] -> [h][d][p] (bf16) ----------------
__global__ __launch_bounds__(256) void vtrans_kernel(
    const unsigned short* __restrict__ v_ws,
    unsigned short* __restrict__ vt_ws)
{
    __shared__ unsigned short T[64][72];
    const int p0 = blockIdx.x * 64;
    const int h  = blockIdx.y;
    const int t  = threadIdx.x;
#pragma unroll
    for (int i = 0; i < 2; ++i) {
        const int e = t + i * 256;
        const int r = e >> 3, cc = (e & 7) * 8;
        const ushort8v val = *(const ushort8v*)(v_ws + (h * TOTAL + p0 + r) * 64 + cc);
        *(ushort8v*)&T[r][cc] = val;
    }
    __syncthreads();
#pragma unroll
    for (int i = 0; i < 2; ++i) {
        const int e = t + i * 256;
        const int d = e >> 3, pc = (e & 7) * 8;
        ushort8v o;
#pragma unroll
        for (int j = 0; j < 8; ++j) o[j] = T[pc + j][d];
        *(ushort8v*)(vt_ws + (h * 64 + d) * TOTAL + p0 + pc) = o;
    }
}

// ---------------- flash attention (bf16 MFMA) ----------------
// grid: x=q-tile(64), y=head, z=batch. 4 waves/block, wave w owns q rows 16w..16w+15.
// batch0: 512 real keys + 1536 analytic zero-keys. batch1: mask via k-tile skip.
__global__ __launch_bounds__(256) void attn_kernel(
    const unsigned short* __restrict__ q_ws,
    const unsigned short* __restrict__ k_ws,
    const unsigned short* __restrict__ vt_ws,
    float* __restrict__ y)
{
    const int qt = blockIdx.x;
    const int h  = blockIdx.y;
    const int b  = blockIdx.z;
    const int nq = b ? 2048 : 512;
    if (qt * 64 >= nq) return;
    const int base = b ? 512 : 0;
    const int nkt  = nq >> 6;
    const int kt0  = (b && (qt * 64 < 512)) ? 8 : 0;
    const float extra = b ? 0.0f : 1536.0f;

    const int t    = threadIdx.x;
    const int w    = t >> 6;
    const int lane = t & 63;
    const int g    = lane >> 4;
    const int c    = lane & 15;

    __shared__ unsigned short K_lds[64][72];
    __shared__ unsigned short V_lds[64][72];   // V^T tile: [d][k]
    __shared__ unsigned short P_lds[64][72];

    // Q frags (held in regs for all k-tiles): A-frag row = lane&15, k-slice = 8*(lane>>4)+32*kk
    const unsigned short* Qrow = q_ws + ((h * TOTAL) + base + qt * 64 + 16 * w + c) * 64;
    const bf16x8 qa0 = *(const bf16x8*)(Qrow + 8 * g);
    const bf16x8 qa1 = *(const bf16x8*)(Qrow + 8 * g + 32);

    float m_old[4], l_old[4];
#pragma unroll
    for (int r = 0; r < 4; ++r) { m_old[r] = NEG_BIG; l_old[r] = 0.f; }
    f32x4 o_acc[4];
#pragma unroll
    for (int n = 0; n < 4; ++n) o_acc[n] = (f32x4){0.f, 0.f, 0.f, 0.f};

    const unsigned short* Kg = k_ws + (h * TOTAL + base) * 64;
    const unsigned short* Vg = vt_ws + h * 64 * TOTAL + base;

    for (int kt = kt0; kt < nkt; ++kt) {
        ushort8v ks[2], vs[2];
#pragma unroll
        for (int i = 0; i < 2; ++i) {
            const int e = t + i * 256;
            const int rr = e >> 3, cc = (e & 7) * 8;
            ks[i] = *(const ushort8v*)(Kg + (kt * 64 + rr) * 64 + cc);
            vs[i] = *(const ushort8v*)(Vg + rr * TOTAL + kt * 64 + cc);
        }
        __syncthreads();   // prior iteration's LDS reads complete
#pragma unroll
        for (int i = 0; i < 2; ++i) {
            const int e = t + i * 256;
            const int rr = e >> 3, cc = (e & 7) * 8;
            *(ushort8v*)&K_lds[rr][cc] = ks[i];
            *(ushort8v*)&V_lds[rr][cc] = vs[i];
        }
        __syncthreads();

        // S = Q K^T : 8 MFMAs; S[q=16w+4g+r][k=16n+c] in s_acc[n][r]
        f32x4 s_acc[4];
#pragma unroll
        for (int n = 0; n < 4; ++n) {
            f32x4 acc = (f32x4){0.f, 0.f, 0.f, 0.f};
            const bf16x8 kb0 = *(const bf16x8*)&K_lds[16 * n + c][8 * g];
            const bf16x8 kb1 = *(const bf16x8*)&K_lds[16 * n + c][8 * g + 32];
            acc = __builtin_amdgcn_mfma_f32_16x16x32_bf16(qa0, kb0, acc, 0, 0, 0);
            acc = __builtin_amdgcn_mfma_f32_16x16x32_bf16(qa1, kb1, acc, 0, 0, 0);
            s_acc[n] = acc;
        }

        float sv[4][4], p_[4][4], corr[4];
#pragma unroll
        for (int n = 0; n < 4; ++n)
#pragma unroll
            for (int r = 0; r < 4; ++r) sv[n][r] = s_acc[n][r] * 0.125f;

#pragma unroll
        for (int r = 0; r < 4; ++r) {
            float tm = fmaxf(fmaxf(sv[0][r], sv[1][r]), fmaxf(sv[2][r], sv[3][r]));
            tm = fmaxf(tm, __shfl_xor(tm, 1));
            tm = fmaxf(tm, __shfl_xor(tm, 2));
            tm = fmaxf(tm, __shfl_xor(tm, 4));
            tm = fmaxf(tm, __shfl_xor(tm, 8));
            const float m_new = fmaxf(m_old[r], tm);
            corr[r] = __expf(m_old[r] - m_new);
            float rs = 0.f;
#pragma unroll
            for (int n = 0; n < 4; ++n) {
                const float pv = __expf(sv[n][r] - m_new);
                p_[n][r] = pv;
                rs += pv;
            }
            rs += __shfl_xor(rs, 1);
            rs += __shfl_xor(rs, 2);
            rs += __shfl_xor(rs, 4);
            rs += __shfl_xor(rs, 8);
            l_old[r] = l_old[r] * corr[r] + rs;
            m_old[r] = m_new;
        }

        // rescale O, write P (wave-local rows -> no barrier needed)
#pragma unroll
        for (int n = 0; n < 4; ++n)
#pragma unroll
            for (int r = 0; r < 4; ++r) {
                o_acc[n][r] *= corr[r];
                P_lds[16 * w + 4 * g + r][16 * n + c] = f2bf(p_[n][r]);
            }

        // O += P V : 8 MFMAs
#pragma unroll
        for (int kk = 0; kk < 2; ++kk) {
            const bf16x8 pa = *(const bf16x8*)&P_lds[16 * w + c][8 * g + 32 * kk];
#pragma unroll
            for (int n = 0; n < 4; ++n) {
                const bf16x8 vb = *(const bf16x8*)&V_lds[16 * n + c][8 * g + 32 * kk];
                o_acc[n] = __builtin_amdgcn_mfma_f32_16x16x32_bf16(pa, vb, o_acc[n], 0, 0, 0);
            }
        }
    }

    // finalize: analytic zero-score keys (batch0) + normalize
    float inv[4];
#pragma unroll
    for (int r = 0; r < 4; ++r) {
        float m = m_old[r], l = l_old[r], so = 1.f;
        if (extra > 0.f) {
            const float mn = fmaxf(m, 0.f);
            const float ccf = __expf(m - mn);
            l = l * ccf + extra * __expf(-mn);
            so = ccf;
        }
        inv[r] = so / l;
    }
    float* yb = y + (base + qt * 64 + 16 * w) * 512 + h * 64;
#pragma unroll
    for (int n = 0; n < 4; ++n)
#pragma unroll
        for (int r = 0; r < 4; ++r)
            yb[(4 * g + r) * 512 + 16 * n + c] = o_acc[n][r] * inv[r];
}

// ---------------- output projection (fp32, +bias) ----------------
__global__ __launch_bounds__(256) void proj_gemm_kernel(
    const float* __restrict__ A,
    const float* __restrict__ W,
    const float* __restrict__ bias,
    float* __restrict__ out)
{
    __shared__ float As[16][68];
    __shared__ float Bs[16][68];
    const int m0 = blockIdx.x * 64;
    const int n0 = blockIdx.y * 64;
    const int t  = threadIdx.x;
    const int tx = t & 15, ty = t >> 4;
    const int lr = t >> 2, lc = (t & 3) * 4;
    float acc[4][4] = {{0.f}};
    const float* aptr = A + (m0 + lr) * 512 + lc;
    const float* bptr = W + (n0 + lr) * 512 + lc;
    for (int kt = 0; kt < 512; kt += 16) {
        const float4 a4 = *(const float4*)(aptr + kt);
        const float4 b4 = *(const float4*)(bptr + kt);
        __syncthreads();
        As[lc + 0][lr] = a4.x; As[lc + 1][lr] = a4.y; As[lc + 2][lr] = a4.z; As[lc + 3][lr] = a4.w;
        Bs[lc + 0][lr] = b4.x; Bs[lc + 1][lr] = b4.y; Bs[lc + 2][lr] = b4.z; Bs[lc + 3][lr] = b4.w;
        __syncthreads();
#pragma unroll
        for (int kk = 0; kk < 16; ++kk) {
            const float4 av = *(const float4*)&As[kk][ty * 4];
            const float4 bv = *(const float4*)&Bs[kk][tx * 4];
            const float a[4] = {av.x, av.y, av.z, av.w};
            const float b[4] = {bv.x, bv.y, bv.z, bv.w};
#pragma unroll
            for (int i = 0; i < 4; ++i)
#pragma unroll
                for (int j = 0; j < 4; ++j)
                    acc[i][j] = fmaf(a[i], b[j], acc[i][j]);
        }
    }
#pragma unroll
    for (int i = 0; i < 4; ++i) {
        const int p = m0 + ty * 4 + i;
#pragma unroll
        for (int j = 0; j < 4; ++j) {
            const int col = n0 + tx * 4 + j;
            out[p * 512 + col] = acc[i][j] + bias[col];
        }
    }
}

extern "C" void kernel_launch(void* const* d_in, const int* in_sizes, int n_in,
                              void* d_out, int out_size, void* d_ws, size_t ws_size,
                              hipStream_t stream) {
    const float* features = (const float*)d_in[0];
    const float* coords   = (const float*)d_in[1];
    const float* qkv_w    = (const float*)d_in[2];
    const float* proj_w   = (const float*)d_in[3];
    const float* proj_b   = (const float*)d_in[4];
    const float* pos_w    = (const float*)d_in[5];
    const float* pos_b    = (const float*)d_in[6];
    float* out = (float*)d_out;

    float* pos_ws = (float*)d_ws;                                   // 2560*64 f32
    unsigned short* q_ws  = (unsigned short*)(pos_ws + TOTAL * 64); // 8*2560*64 bf16
    unsigned short* k_ws  = q_ws  + 8 * TOTAL * 64;
    unsigned short* v_ws  = k_ws  + 8 * TOTAL * 64;
    unsigned short* vt_ws = v_ws  + 8 * TOTAL * 64;
    float* y_ws = (float*)(vt_ws + 8 * TOTAL * 64);                 // 2560*512 f32

    pos_kernel<<<dim3(TOTAL), dim3(64), 0, stream>>>(coords, pos_w, pos_b, pos_ws);
    qkv_gemm_kernel<<<dim3(TOTAL / 64, 1536 / 64), dim3(256), 0, stream>>>(
        features, qkv_w, pos_ws, q_ws, k_ws, v_ws);
    vtrans_kernel<<<dim3(TOTAL / 64, 8), dim3(256), 0, stream>>>(v_ws, vt_ws);
    attn_kernel<<<dim3(32, 8, 2), dim3(256), 0, stream>>>(q_ws, k_ws, vt_ws, y_ws);
    proj_gemm_kernel<<<dim3(TOTAL / 64, 512 / 64), dim3(256), 0, stream>>>(
        y_ws, proj_w, proj_b, out);
}

// Round 4
// 131.350 us; speedup vs baseline: 2.3560x; 1.1889x over previous
//
#include <hip/hip_runtime.h>
#include <math.h>

#define TOTAL 2560
#define NEG_BIG (-1e30f)

typedef __bf16 bf16x8 __attribute__((ext_vector_type(8)));
typedef float f32x4 __attribute__((ext_vector_type(4)));
typedef unsigned short ushort8v __attribute__((ext_vector_type(8)));

__device__ inline unsigned short f2bf(float f) {
    unsigned u = __builtin_bit_cast(unsigned, f);
    u += 0x7fff + ((u >> 16) & 1);
    return (unsigned short)(u >> 16);
}

// ---------------- positional encoding ----------------
__global__ __launch_bounds__(64) void pos_kernel(
    const float* __restrict__ coords,
    const float* __restrict__ pos_w,
    const float* __restrict__ pos_b,
    float* __restrict__ pos_out)
{
    __shared__ float enc[100];
    const int p = blockIdx.x;
    const int t = threadIdx.x;
    const float c0 = coords[p * 3 + 0];
    const float c1 = coords[p * 3 + 1];
    const float c2 = coords[p * 3 + 2];
    for (int i = t; i < 99; i += 64) {
        float v;
        if (i < 96) {
            const int d = i >> 5;
            const int j = i & 31;
            const float cv = (d == 0) ? c0 : ((d == 1) ? c1 : c2);
            const float freq = exp2f((float)(j & 15)) * 3.14159265358979323846f;
            const float sc = cv * freq;
            v = (j < 16) ? sinf(sc) : cosf(sc);
        } else {
            v = (i == 96) ? c0 : ((i == 97) ? c1 : c2);
        }
        enc[i] = v;
    }
    __syncthreads();
    float acc = pos_b[t];
    const float* w = pos_w + t * 99;
    for (int i = 0; i < 99; ++i) acc = fmaf(enc[i], w[i], acc);
    pos_out[p * 64 + t] = acc;
}

// ---------------- fp32 -> bf16 cast (features, qkv_w, proj_w) ----------------
// seg s = 8 contiguous elems. features: 2560*64 segs; qkv_w: 1536*64; proj_w: 512*64.
__global__ __launch_bounds__(256) void cast_kernel(
    const float* __restrict__ f,  const float* __restrict__ qw, const float* __restrict__ pw,
    unsigned short* __restrict__ fb, unsigned short* __restrict__ qwb, unsigned short* __restrict__ pwb)
{
    const int s = blockIdx.x * 256 + threadIdx.x;
    const float* src; unsigned short* dst; int ls;
    if (s < 163840)      { src = f;  dst = fb;  ls = s; }
    else if (s < 262144) { src = qw; dst = qwb; ls = s - 163840; }
    else                 { src = pw; dst = pwb; ls = s - 262144; }
    const float4 x0 = *(const float4*)(src + ls * 8);
    const float4 x1 = *(const float4*)(src + ls * 8 + 4);
    ushort8v o;
    o[0] = f2bf(x0.x); o[1] = f2bf(x0.y); o[2] = f2bf(x0.z); o[3] = f2bf(x0.w);
    o[4] = f2bf(x1.x); o[5] = f2bf(x1.y); o[6] = f2bf(x1.z); o[7] = f2bf(x1.w);
    *(ushort8v*)(dst + ls * 8) = o;
}

// ---------------- QKV GEMM: bf16 MFMA, 128x128 tile, BK=64 ----------------
// A: feat_bf [2560][512]; B: qkvw_bf [1536][512] (N x K). XOR-swizzled LDS (T2).
__global__ __launch_bounds__(256) void qkv_mfma_kernel(
    const unsigned short* __restrict__ A,
    const unsigned short* __restrict__ Bm,
    const float* __restrict__ pos,
    unsigned short* __restrict__ q_ws,
    unsigned short* __restrict__ k_ws,
    unsigned short* __restrict__ v_ws)
{
    __shared__ unsigned short A_lds[128 * 64];
    __shared__ unsigned short B_lds[128 * 64];
    const int m0 = blockIdx.x * 128;
    const int n0 = blockIdx.y * 128;
    const int t = threadIdx.x;
    const int w = t >> 6, l = t & 63;
    const int wr = w >> 1, wc = w & 1;
    const int c = l & 15, g = l >> 4;
    const int lr8 = l >> 3, cs = l & 7;

    f32x4 acc[4][4];
#pragma unroll
    for (int mi = 0; mi < 4; ++mi)
#pragma unroll
        for (int ni = 0; ni < 4; ++ni) acc[mi][ni] = (f32x4){0.f, 0.f, 0.f, 0.f};

    for (int kt = 0; kt < 8; ++kt) {
        uint4 areg[4], breg[4];
#pragma unroll
        for (int i = 0; i < 4; ++i) {
            const int row = w * 32 + i * 8 + lr8;
            areg[i] = *(const uint4*)(A  + (m0 + row) * 512 + kt * 64 + cs * 8);
            breg[i] = *(const uint4*)(Bm + (n0 + row) * 512 + kt * 64 + cs * 8);
        }
        __syncthreads();
#pragma unroll
        for (int i = 0; i < 4; ++i) {
            const int row = w * 32 + i * 8 + lr8;
            const int slot = cs ^ (row & 7);
            *(uint4*)&A_lds[row * 64 + slot * 8] = areg[i];
            *(uint4*)&B_lds[row * 64 + slot * 8] = breg[i];
        }
        __syncthreads();
#pragma unroll
        for (int kk = 0; kk < 2; ++kk) {
            bf16x8 af[4], bfr[4];
#pragma unroll
            for (int mi = 0; mi < 4; ++mi) {
                const int row = wr * 64 + mi * 16 + c;
                af[mi] = *(const bf16x8*)&A_lds[row * 64 + ((g + 4 * kk) ^ (row & 7)) * 8];
            }
#pragma unroll
            for (int ni = 0; ni < 4; ++ni) {
                const int row = wc * 64 + ni * 16 + c;
                bfr[ni] = *(const bf16x8*)&B_lds[row * 64 + ((g + 4 * kk) ^ (row & 7)) * 8];
            }
#pragma unroll
            for (int mi = 0; mi < 4; ++mi)
#pragma unroll
                for (int ni = 0; ni < 4; ++ni)
                    acc[mi][ni] = __builtin_amdgcn_mfma_f32_16x16x32_bf16(af[mi], bfr[ni], acc[mi][ni], 0, 0, 0);
        }
    }

    const int which = n0 >> 9;   // block's 128-col slab lies in one of q/k/v
#pragma unroll
    for (int mi = 0; mi < 4; ++mi)
#pragma unroll
        for (int ni = 0; ni < 4; ++ni) {
            const int col = n0 + wc * 64 + ni * 16 + c;
            const int h = (col >> 6) & 7, dd = col & 63;
#pragma unroll
            for (int r = 0; r < 4; ++r) {
                const int p = m0 + wr * 64 + mi * 16 + 4 * g + r;
                float v = acc[mi][ni][r];
                if (which < 2) v += pos[p * 64 + dd];
                const unsigned short bv = f2bf(v);
                const int idx = (h * TOTAL + p) * 64 + dd;
                if (which == 0)      q_ws[idx] = bv;
                else if (which == 1) k_ws[idx] = bv;
                else                 v_ws[idx] = bv;
            }
        }
}

// ---------------- V transpose: [h][p][d] -> [h][d][p] (bf16) ----------------
__global__ __launch_bounds__(256) void vtrans_kernel(
    const unsigned short* __restrict__ v_ws,
    unsigned short* __restrict__ vt_ws)
{
    __shared__ unsigned short T[64][72];
    const int p0 = blockIdx.x * 64;
    const int h  = blockIdx.y;
    const int t  = threadIdx.x;
#pragma unroll
    for (int i = 0; i < 2; ++i) {
        const int e = t + i * 256;
        const int r = e >> 3, cc = (e & 7) * 8;
        const ushort8v val = *(const ushort8v*)(v_ws + (h * TOTAL + p0 + r) * 64 + cc);
        *(ushort8v*)&T[r][cc] = val;
    }
    __syncthreads();
#pragma unroll
    for (int i = 0; i < 2; ++i) {
        const int e = t + i * 256;
        const int d = e >> 3, pc = (e & 7) * 8;
        ushort8v o;
#pragma unroll
        for (int j = 0; j < 8; ++j) o[j] = T[pc + j][d];
        *(ushort8v*)(vt_ws + (h * 64 + d) * TOTAL + p0 + pc) = o;
    }
}

// ---------------- flash attention (bf16 MFMA) ----------------
__global__ __launch_bounds__(256) void attn_kernel(
    const unsigned short* __restrict__ q_ws,
    const unsigned short* __restrict__ k_ws,
    const unsigned short* __restrict__ vt_ws,
    unsigned short* __restrict__ y)
{
    const int qt = blockIdx.x;
    const int h  = blockIdx.y;
    const int b  = blockIdx.z;
    const int nq = b ? 2048 : 512;
    if (qt * 64 >= nq) return;
    const int base = b ? 512 : 0;
    const int nkt  = nq >> 6;
    const int kt0  = (b && (qt * 64 < 512)) ? 8 : 0;
    const float extra = b ? 0.0f : 1536.0f;

    const int t    = threadIdx.x;
    const int w    = t >> 6;
    const int lane = t & 63;
    const int g    = lane >> 4;
    const int c    = lane & 15;

    __shared__ unsigned short K_lds[64][72];
    __shared__ unsigned short V_lds[64][72];   // V^T tile: [d][k]
    __shared__ unsigned short P_lds[64][72];

    const unsigned short* Qrow = q_ws + ((h * TOTAL) + base + qt * 64 + 16 * w + c) * 64;
    const bf16x8 qa0 = *(const bf16x8*)(Qrow + 8 * g);
    const bf16x8 qa1 = *(const bf16x8*)(Qrow + 8 * g + 32);

    float m_old[4], l_old[4];
#pragma unroll
    for (int r = 0; r < 4; ++r) { m_old[r] = NEG_BIG; l_old[r] = 0.f; }
    f32x4 o_acc[4];
#pragma unroll
    for (int n = 0; n < 4; ++n) o_acc[n] = (f32x4){0.f, 0.f, 0.f, 0.f};

    const unsigned short* Kg = k_ws + (h * TOTAL + base) * 64;
    const unsigned short* Vg = vt_ws + h * 64 * TOTAL + base;

    for (int kt = kt0; kt < nkt; ++kt) {
        ushort8v ks[2], vs[2];
#pragma unroll
        for (int i = 0; i < 2; ++i) {
            const int e = t + i * 256;
            const int rr = e >> 3, cc = (e & 7) * 8;
            ks[i] = *(const ushort8v*)(Kg + (kt * 64 + rr) * 64 + cc);
            vs[i] = *(const ushort8v*)(Vg + rr * TOTAL + kt * 64 + cc);
        }
        __syncthreads();
#pragma unroll
        for (int i = 0; i < 2; ++i) {
            const int e = t + i * 256;
            const int rr = e >> 3, cc = (e & 7) * 8;
            *(ushort8v*)&K_lds[rr][cc] = ks[i];
            *(ushort8v*)&V_lds[rr][cc] = vs[i];
        }
        __syncthreads();

        f32x4 s_acc[4];
#pragma unroll
        for (int n = 0; n < 4; ++n) {
            f32x4 acc = (f32x4){0.f, 0.f, 0.f, 0.f};
            const bf16x8 kb0 = *(const bf16x8*)&K_lds[16 * n + c][8 * g];
            const bf16x8 kb1 = *(const bf16x8*)&K_lds[16 * n + c][8 * g + 32];
            acc = __builtin_amdgcn_mfma_f32_16x16x32_bf16(qa0, kb0, acc, 0, 0, 0);
            acc = __builtin_amdgcn_mfma_f32_16x16x32_bf16(qa1, kb1, acc, 0, 0, 0);
            s_acc[n] = acc;
        }

        float sv[4][4], p_[4][4], corr[4];
#pragma unroll
        for (int n = 0; n < 4; ++n)
#pragma unroll
            for (int r = 0; r < 4; ++r) sv[n][r] = s_acc[n][r] * 0.125f;

#pragma unroll
        for (int r = 0; r < 4; ++r) {
            float tm = fmaxf(fmaxf(sv[0][r], sv[1][r]), fmaxf(sv[2][r], sv[3][r]));
            tm = fmaxf(tm, __shfl_xor(tm, 1));
            tm = fmaxf(tm, __shfl_xor(tm, 2));
            tm = fmaxf(tm, __shfl_xor(tm, 4));
            tm = fmaxf(tm, __shfl_xor(tm, 8));
            const float m_new = fmaxf(m_old[r], tm);
            corr[r] = __expf(m_old[r] - m_new);
            float rs = 0.f;
#pragma unroll
            for (int n = 0; n < 4; ++n) {
                const float pv = __expf(sv[n][r] - m_new);
                p_[n][r] = pv;
                rs += pv;
            }
            rs += __shfl_xor(rs, 1);
            rs += __shfl_xor(rs, 2);
            rs += __shfl_xor(rs, 4);
            rs += __shfl_xor(rs, 8);
            l_old[r] = l_old[r] * corr[r] + rs;
            m_old[r] = m_new;
        }

#pragma unroll
        for (int n = 0; n < 4; ++n)
#pragma unroll
            for (int r = 0; r < 4; ++r) {
                o_acc[n][r] *= corr[r];
                P_lds[16 * w + 4 * g + r][16 * n + c] = f2bf(p_[n][r]);
            }

#pragma unroll
        for (int kk = 0; kk < 2; ++kk) {
            const bf16x8 pa = *(const bf16x8*)&P_lds[16 * w + c][8 * g + 32 * kk];
#pragma unroll
            for (int n = 0; n < 4; ++n) {
                const bf16x8 vb = *(const bf16x8*)&V_lds[16 * n + c][8 * g + 32 * kk];
                o_acc[n] = __builtin_amdgcn_mfma_f32_16x16x32_bf16(pa, vb, o_acc[n], 0, 0, 0);
            }
        }
    }

    float inv[4];
#pragma unroll
    for (int r = 0; r < 4; ++r) {
        float m = m_old[r], l = l_old[r], so = 1.f;
        if (extra > 0.f) {
            const float mn = fmaxf(m, 0.f);
            const float ccf = __expf(m - mn);
            l = l * ccf + extra * __expf(-mn);
            so = ccf;
        }
        inv[r] = so / l;
    }
    unsigned short* yb = y + (base + qt * 64 + 16 * w) * 512 + h * 64;
#pragma unroll
    for (int n = 0; n < 4; ++n)
#pragma unroll
        for (int r = 0; r < 4; ++r)
            yb[(4 * g + r) * 512 + 16 * n + c] = f2bf(o_acc[n][r] * inv[r]);
}

// ---------------- output projection: bf16 MFMA + bias, fp32 out ----------------
__global__ __launch_bounds__(256) void proj_mfma_kernel(
    const unsigned short* __restrict__ A,    // y_bf [2560][512]
    const unsigned short* __restrict__ Bm,   // projw_bf [512][512]
    const float* __restrict__ bias,
    float* __restrict__ out)
{
    __shared__ unsigned short A_lds[128 * 64];
    __shared__ unsigned short B_lds[128 * 64];
    const int m0 = blockIdx.x * 128;
    const int n0 = blockIdx.y * 128;
    const int t = threadIdx.x;
    const int w = t >> 6, l = t & 63;
    const int wr = w >> 1, wc = w & 1;
    const int c = l & 15, g = l >> 4;
    const int lr8 = l >> 3, cs = l & 7;

    f32x4 acc[4][4];
#pragma unroll
    for (int mi = 0; mi < 4; ++mi)
#pragma unroll
        for (int ni = 0; ni < 4; ++ni) acc[mi][ni] = (f32x4){0.f, 0.f, 0.f, 0.f};

    for (int kt = 0; kt < 8; ++kt) {
        uint4 areg[4], breg[4];
#pragma unroll
        for (int i = 0; i < 4; ++i) {
            const int row = w * 32 + i * 8 + lr8;
            areg[i] = *(const uint4*)(A  + (m0 + row) * 512 + kt * 64 + cs * 8);
            breg[i] = *(const uint4*)(Bm + (n0 + row) * 512 + kt * 64 + cs * 8);
        }
        __syncthreads();
#pragma unroll
        for (int i = 0; i < 4; ++i) {
            const int row = w * 32 + i * 8 + lr8;
            const int slot = cs ^ (row & 7);
            *(uint4*)&A_lds[row * 64 + slot * 8] = areg[i];
            *(uint4*)&B_lds[row * 64 + slot * 8] = breg[i];
        }
        __syncthreads();
#pragma unroll
        for (int kk = 0; kk < 2; ++kk) {
            bf16x8 af[4], bfr[4];
#pragma unroll
            for (int mi = 0; mi < 4; ++mi) {
                const int row = wr * 64 + mi * 16 + c;
                af[mi] = *(const bf16x8*)&A_lds[row * 64 + ((g + 4 * kk) ^ (row & 7)) * 8];
            }
#pragma unroll
            for (int ni = 0; ni < 4; ++ni) {
                const int row = wc * 64 + ni * 16 + c;
                bfr[ni] = *(const bf16x8*)&B_lds[row * 64 + ((g + 4 * kk) ^ (row & 7)) * 8];
            }
#pragma unroll
            for (int mi = 0; mi < 4; ++mi)
#pragma unroll
                for (int ni = 0; ni < 4; ++ni)
                    acc[mi][ni] = __builtin_amdgcn_mfma_f32_16x16x32_bf16(af[mi], bfr[ni], acc[mi][ni], 0, 0, 0);
        }
    }

#pragma unroll
    for (int mi = 0; mi < 4; ++mi)
#pragma unroll
        for (int ni = 0; ni < 4; ++ni) {
            const int col = n0 + wc * 64 + ni * 16 + c;
            const float bv = bias[col];
#pragma unroll
            for (int r = 0; r < 4; ++r) {
                const int p = m0 + wr * 64 + mi * 16 + 4 * g + r;
                out[p * 512 + col] = acc[mi][ni][r] + bv;
            }
        }
}

extern "C" void kernel_launch(void* const* d_in, const int* in_sizes, int n_in,
                              void* d_out, int out_size, void* d_ws, size_t ws_size,
                              hipStream_t stream) {
    const float* features = (const float*)d_in[0];
    const float* coords   = (const float*)d_in[1];
    const float* qkv_w    = (const float*)d_in[2];
    const float* proj_w   = (const float*)d_in[3];
    const float* proj_b   = (const float*)d_in[4];
    const float* pos_w    = (const float*)d_in[5];
    const float* pos_b    = (const float*)d_in[6];
    float* out = (float*)d_out;

    float* pos_ws = (float*)d_ws;                                    // 2560*64 f32
    unsigned short* feat_bf  = (unsigned short*)(pos_ws + TOTAL * 64);
    unsigned short* qkvw_bf  = feat_bf + 2560 * 512;
    unsigned short* projw_bf = qkvw_bf + 1536 * 512;
    unsigned short* q_ws  = projw_bf + 512 * 512;
    unsigned short* k_ws  = q_ws  + 8 * TOTAL * 64;
    unsigned short* v_ws  = k_ws  + 8 * TOTAL * 64;
    unsigned short* vt_ws = v_ws  + 8 * TOTAL * 64;
    unsigned short* y_bf  = vt_ws + 8 * TOTAL * 64;

    pos_kernel<<<dim3(TOTAL), dim3(64), 0, stream>>>(coords, pos_w, pos_b, pos_ws);
    cast_kernel<<<dim3(1152), dim3(256), 0, stream>>>(
        features, qkv_w, proj_w, feat_bf, qkvw_bf, projw_bf);
    qkv_mfma_kernel<<<dim3(2560 / 128, 1536 / 128), dim3(256), 0, stream>>>(
        feat_bf, qkvw_bf, pos_ws, q_ws, k_ws, v_ws);
    vtrans_kernel<<<dim3(TOTAL / 64, 8), dim3(256), 0, stream>>>(v_ws, vt_ws);
    attn_kernel<<<dim3(32, 8, 2), dim3(256), 0, stream>>>(q_ws, k_ws, vt_ws, y_bf);
    proj_mfma_kernel<<<dim3(2560 / 128, 512 / 128), dim3(256), 0, stream>>>(
        y_bf, projw_bf, proj_b, out);
}